// Round 4
// baseline (685.921 us; speedup 1.0000x reference)
//
#include <hip/hip_runtime.h>
#include <stdint.h>

// Problem constants (fixed by the reference)
#define Bc 4
#define Sc 2048
#define Dc 768
#define Kc 8192
#define NSc 2
#define Mc (Bc*Sc)                      // 8192 tokens
#define EMB_ELEMS ((size_t)Mc*NSc*Dc)   // emb output floats; indices follow

typedef __attribute__((ext_vector_type(8))) __bf16 bf16x8;
typedef __attribute__((ext_vector_type(4))) float f32x4;
typedef __attribute__((ext_vector_type(4))) unsigned short u16x4;

__device__ __forceinline__ unsigned short f2bf(float f){
  unsigned int u = __float_as_uint(f);
  u += 0x7FFFu + ((u >> 16) & 1u);       // round-to-nearest-even
  return (unsigned short)(u >> 16);
}
__device__ __forceinline__ float bf2f(unsigned short h){
  return __uint_as_float(((unsigned int)h) << 16);
}

// ---------------- K0: convert x,w f32 -> bf16 (into ws) ----------------
__global__ __launch_bounds__(256) void k_convert(const float4* __restrict__ x,
                                                 const float4* __restrict__ w,
                                                 u16x4* __restrict__ xb,
                                                 u16x4* __restrict__ wb){
  int i = blockIdx.x * 256 + threadIdx.x;
  float4 v = x[i];
  u16x4 o;
  o.x = f2bf(v.x); o.y = f2bf(v.y); o.z = f2bf(v.z); o.w = f2bf(v.w);
  xb[i] = o;
  v = w[i];
  o.x = f2bf(v.x); o.y = f2bf(v.y); o.z = f2bf(v.z); o.w = f2bf(v.w);
  wb[i] = o;
}

// ---------------- K1: bf16 MFMA GEMM + in-loop gumbel tile-max ---------------
// logits[m][k] bf16 at row stride 32768 ushorts (first 16KB of each 64KB row of
// the indices output region). UB stats f32[256] at byte offset 16384 of each
// row: UB[t][s][tile64] = max_l(tile) + max_g(tile), tile = 64 columns.
// Gumbel is streamed DURING the K-loop (2 float4/thread/iter, pipelined one
// iteration deep so latency rides the existing barrier vmcnt drain).
#define BM 128
#define BN 128
#define BK 32

__global__ __launch_bounds__(256) void k_gemm(const unsigned short* __restrict__ xb,
                                              const unsigned short* __restrict__ wb,
                                              const float* __restrict__ gumbel,
                                              unsigned short* __restrict__ logits){
  __shared__ unsigned short As[BM*BK];   // 8 KB linear (global_load_lds dest)
  __shared__ unsigned short Bs[BN*BK];   // 8 KB
  __shared__ float gmaxbuf[256][2];      // per (row=t_local*2+s, tile) gumbel max
  __shared__ float lbuf[128][2];         // per (t_local, tile) logit max

  const int tid  = threadIdx.x;
  const int lane = tid & 63;
  const int wid  = tid >> 6;             // 4 waves, 2x2 -> each owns 64x64 out
  const int wm   = wid >> 1;
  const int wn   = wid & 1;
  const int bm0  = blockIdx.y * BM;
  const int bn0  = blockIdx.x * BN;

  f32x4 acc[4][4] = {};

  const int srow  = tid >> 2;
  const int scole = (tid & 3) * 8;
  const unsigned short* aS0 = xb + (size_t)(bm0 + srow) * Dc + scole;
  const unsigned short* aS1 = xb + (size_t)(bm0 + 64 + srow) * Dc + scole;
  const unsigned short* bS0 = wb + (size_t)(bn0 + srow) * Dc + scole;
  const unsigned short* bS1 = wb + (size_t)(bn0 + 64 + srow) * Dc + scole;
  unsigned short* aD0 = &As[wid * 512];
  unsigned short* aD1 = &As[2048 + wid * 512];
  unsigned short* bD0 = &Bs[wid * 512];
  unsigned short* bD1 = &Bs[2048 + wid * 512];

  const int fr = lane & 15;
  const int fk = (lane >> 4) * 8;

  // gumbel streaming ids: 8 groups of 32 threads; each group = one 512B row seg
  const int grp = tid >> 5;              // 0..7  (row within pass-set)
  const int gc4 = tid & 31;              // float4 column
  const int gtl = (tid >> 4) & 1;        // 64-col tile within group

  float4 ga, gb;                         // pipelined gumbel registers

  for (int it = 0; it < Dc/BK; ++it) {   // 24 iterations
    __syncthreads();                     // drains prev iter's gumbel loads too
    const int kt = it * BK;
    __builtin_amdgcn_global_load_lds((const __attribute__((address_space(1))) void*)(aS0 + kt),
                                     (__attribute__((address_space(3))) void*)aD0, 16, 0, 0);
    __builtin_amdgcn_global_load_lds((const __attribute__((address_space(1))) void*)(aS1 + kt),
                                     (__attribute__((address_space(3))) void*)aD1, 16, 0, 0);
    __builtin_amdgcn_global_load_lds((const __attribute__((address_space(1))) void*)(bS0 + kt),
                                     (__attribute__((address_space(3))) void*)bD0, 16, 0, 0);
    __builtin_amdgcn_global_load_lds((const __attribute__((address_space(1))) void*)(bS1 + kt),
                                     (__attribute__((address_space(3))) void*)bD1, 16, 0, 0);
    __syncthreads();

    // consume gumbel set it-1 (loaded last iter, drained by this iter's barrier)
    if (it >= 1 && it <= 16) {
      const int j = it - 1;
      const int r0 = j*16 + grp, r1 = j*16 + 8 + grp;
      float m = fmaxf(fmaxf(ga.x, ga.y), fmaxf(ga.z, ga.w));
      m = fmaxf(m, __shfl_xor(m, 1)); m = fmaxf(m, __shfl_xor(m, 2));
      m = fmaxf(m, __shfl_xor(m, 4)); m = fmaxf(m, __shfl_xor(m, 8));
      if ((tid & 15) == 0) gmaxbuf[r0][gtl] = m;
      m = fmaxf(fmaxf(gb.x, gb.y), fmaxf(gb.z, gb.w));
      m = fmaxf(m, __shfl_xor(m, 1)); m = fmaxf(m, __shfl_xor(m, 2));
      m = fmaxf(m, __shfl_xor(m, 4)); m = fmaxf(m, __shfl_xor(m, 8));
      if ((tid & 15) == 0) gmaxbuf[r1][gtl] = m;
    }
    // issue gumbel set `it` (consumed next iter). rows r = set*16 + {grp, 8+grp};
    // row r -> (t_local = r>>1, s = r&1).
    if (it < 16) {
      const int r0 = it*16 + grp, r1 = it*16 + 8 + grp;
      ga = *(const float4*)(gumbel + ((size_t)(bm0 + (r0 >> 1)) * NSc + (r0 & 1)) * Kc + bn0 + gc4*4);
      gb = *(const float4*)(gumbel + ((size_t)(bm0 + (r1 >> 1)) * NSc + (r1 & 1)) * Kc + bn0 + gc4*4);
    }

    bf16x8 a[4], b[4];
    #pragma unroll
    for (int i = 0; i < 4; i++) {
      a[i] = *(const bf16x8*)&As[(wm*64 + i*16 + fr) * BK + fk];
      b[i] = *(const bf16x8*)&Bs[(wn*64 + i*16 + fr) * BK + fk];
    }
    #pragma unroll
    for (int i = 0; i < 4; i++)
      #pragma unroll
      for (int j = 0; j < 4; j++)
        acc[i][j] = __builtin_amdgcn_mfma_f32_16x16x32_bf16(a[i], b[j], acc[i][j], 0, 0, 0);
  }

  // C-write. C/D layout: col = lane&15, row = (lane>>4)*4 + reg (validated)
  const int crow0 = bm0 + wm*64 + (lane >> 4) * 4;
  const int ccol0 = bn0 + wn*64 + (lane & 15);
  #pragma unroll
  for (int i = 0; i < 4; i++)
    #pragma unroll
    for (int j = 0; j < 4; j++)
      #pragma unroll
      for (int r = 0; r < 4; r++)
        logits[(size_t)(crow0 + i*16 + r) * 32768 + (ccol0 + j*16)] = f2bf(acc[i][j][r]);

  // max_l per (token, 64-col tile) from registers
  #pragma unroll
  for (int i = 0; i < 4; i++)
    #pragma unroll
    for (int r = 0; r < 4; r++) {
      float m = fmaxf(fmaxf(acc[i][0][r], acc[i][1][r]), fmaxf(acc[i][2][r], acc[i][3][r]));
      m = fmaxf(m, __shfl_xor(m, 1)); m = fmaxf(m, __shfl_xor(m, 2));
      m = fmaxf(m, __shfl_xor(m, 4)); m = fmaxf(m, __shfl_xor(m, 8));
      if ((lane & 15) == 0) lbuf[wm*64 + i*16 + (lane >> 4)*4 + r][wn] = m;
    }
  __syncthreads();

  // UB = max_l + max_g -> stats at float offset 4096 of each 16384-float row
  float* statsf = (float*)logits;
  #pragma unroll
  for (int p = 0; p < 2; ++p) {
    const int e = p*256 + tid;           // 512 entries: t_local*4 + s*2 + tile
    const int tl = e >> 2, s = (e >> 1) & 1, ti = e & 1;
    const float ub = lbuf[tl][ti] + gmaxbuf[tl*2 + s][ti];
    statsf[(size_t)(bm0 + tl) * 16384 + 4096 + s*128 + (blockIdx.x*2 + ti)] = ub;
  }
}

// ---------------- K2: select via UB pruning + exact refine + outputs ---------
#define MARGIN 0.125f

__global__ __launch_bounds__(256) void k_select(const unsigned short* logits,   // aliases out_ind!
                                                const float* __restrict__ gumbel,
                                                const float* __restrict__ x,
                                                const float* __restrict__ w,
                                                const float* __restrict__ emb_tab,
                                                float* __restrict__ out_emb,
                                                float* out_ind){
  const int t   = blockIdx.x;
  const int tid = threadIdx.x;
  const int lane = tid & 63, wid = tid >> 6;

  __shared__ int   cand_k[16];
  __shared__ float cand_g[16];
  __shared__ int   cand_cnt;
  __shared__ int   sel_idx[NSc];

  const unsigned short* lrow = logits + (size_t)t * 32768;

  // ---- decide argmax for BOTH samples before any write (stats/logits alias out_ind)
  for (int s = 0; s < NSc; ++s) {
    if (tid == 0) cand_cnt = 0;
    __syncthreads();

    if (wid == 0) {
      const float* ub   = (const float*)lrow + 4096 + s*128;   // 128 tile UBs
      const float* grow = gumbel + ((size_t)t*NSc + s)*Kc;
      const float u0 = ub[lane], u1 = ub[64 + lane];
      // argmax-UB tile
      float bv = fmaxf(u0, u1); int bt = (u1 > u0) ? lane + 64 : lane;
      #pragma unroll
      for (int off = 1; off < 64; off <<= 1) {
        const float ov = __shfl_xor(bv, off); const int ot = __shfl_xor(bt, off);
        if (ov > bv || (ov == bv && ot < bt)) { bv = ov; bt = ot; }
      }
      // exact lower bound: scan best-UB tile (64 lanes <-> 64 cols)
      const int kb = bt*64 + lane;
      float lb = bf2f(lrow[kb]) + grow[kb];
      #pragma unroll
      for (int off = 1; off < 64; off <<= 1) lb = fmaxf(lb, __shfl_xor(lb, off));
      // suspects: UB >= LB - 2*MARGIN (covers bf16 slack both directions)
      const float thrS = lb - 2.0f*MARGIN;
      const unsigned long long m0 = __ballot(u0 >= thrS);
      const unsigned long long m1 = __ballot(u1 >= thrS);
      // phase A: approx global max over suspect tiles
      float va = lb;
      for (int h = 0; h < 2; ++h) {
        unsigned long long mask = h ? m1 : m0;
        while (mask) {
          const int tile = (__ffsll((unsigned long long)mask) - 1) + h*64;
          mask &= mask - 1;
          const int k = tile*64 + lane;
          va = fmaxf(va, bf2f(lrow[k]) + grow[k]);
        }
      }
      #pragma unroll
      for (int off = 1; off < 64; off <<= 1) va = fmaxf(va, __shfl_xor(va, off));
      // phase B: collect candidates within MARGIN of approx max
      const float thrC = va - MARGIN;
      for (int h = 0; h < 2; ++h) {
        unsigned long long mask = h ? m1 : m0;
        while (mask) {
          const int tile = (__ffsll((unsigned long long)mask) - 1) + h*64;
          mask &= mask - 1;
          const int k = tile*64 + lane;
          const float v = bf2f(lrow[k]) + grow[k];
          if (v >= thrC) {
            const int p = atomicAdd(&cand_cnt, 1);
            if (p < 16) cand_k[p] = k;
          }
        }
      }
    }
    __syncthreads();

    const int cnt = min(cand_cnt, 16);
    if (cnt == 1) {
      if (tid == 0) sel_idx[s] = cand_k[0];
    } else {
      // exact refine: wave `wid` takes candidates wid, wid+4, ...
      const float* grow = gumbel + ((size_t)t*NSc + s)*Kc;
      for (int c = wid; c < cnt; c += 4) {
        const int kc = cand_k[c];
        const float* wr = w + (size_t)kc * Dc;
        const float* xr = x + (size_t)t * Dc;
        double accd = 0.0;
        for (int d = lane; d < Dc; d += 64) accd += (double)xr[d] * (double)wr[d];
        #pragma unroll
        for (int off = 32; off; off >>= 1) accd += __shfl_xor(accd, off);
        if (lane == 0) cand_g[c] = (float)accd + grow[kc];
      }
      __syncthreads();
      if (tid == 0) {
        float bg = -1e30f; int bk = Kc;
        for (int c = 0; c < cnt; ++c) {
          const float gg = cand_g[c]; const int kk = cand_k[c];
          if (gg > bg || (gg == bg && kk < bk)) { bg = gg; bk = kk; }
        }
        sel_idx[s] = bk;
      }
    }
    __syncthreads();
  }

  // ---- writes: one-hot indices rows + embedding gathers
  #pragma unroll
  for (int s = 0; s < NSc; ++s) {
    const int idx = sel_idx[s];
    float* irow = out_ind + ((size_t)t*NSc + s)*Kc;
    #pragma unroll
    for (int j = 0; j < 8; ++j) {
      const int k0 = j*1024 + tid*4;
      float4 z = {0.f, 0.f, 0.f, 0.f};
      const int d = idx - k0;
      if (d == 0) z.x = 1.0f; else if (d == 1) z.y = 1.0f;
      else if (d == 2) z.z = 1.0f; else if (d == 3) z.w = 1.0f;
      ((float4*)irow)[j*256 + tid] = z;
    }
    const float* er = emb_tab + (size_t)idx * Dc;
    float* eo = out_emb + ((size_t)t*NSc + s)*Dc;
    for (int d = tid; d < Dc; d += 256) eo[d] = er[d];
  }
}

extern "C" void kernel_launch(void* const* d_in, const int* in_sizes, int n_in,
                              void* d_out, int out_size, void* d_ws, size_t ws_size,
                              hipStream_t stream) {
  const float* x   = (const float*)d_in[0];
  const float* w   = (const float*)d_in[1];
  const float* emb = (const float*)d_in[2];
  const float* gum = (const float*)d_in[3];

  float* out_emb = (float*)d_out;
  float* out_ind = out_emb + EMB_ELEMS;
  unsigned short* logits = (unsigned short*)out_ind;   // row t at ushort t*32768; stats f32 at +4096 floats

  unsigned short* xb = (unsigned short*)d_ws;           // [M][D] bf16 (12.6 MB)
  unsigned short* wb = xb + (size_t)Mc * Dc;            // [K][D] bf16 (12.6 MB)

  const int n4 = (Mc * Dc) / 4;
  k_convert<<<n4 / 256, 256, 0, stream>>>((const float4*)x, (const float4*)w,
                                          (u16x4*)xb, (u16x4*)wb);
  dim3 gg(Kc / BN, Mc / BM);
  k_gemm<<<gg, 256, 0, stream>>>(xb, wb, gum, logits);
  k_select<<<Mc, 256, 0, stream>>>(logits, gum, x, w, emb, out_emb, out_ind);
}